// Round 5
// baseline (311.740 us; speedup 1.0000x reference)
//
#include <hip/hip_runtime.h>
#include <math.h>

// WavelengthDependentPropagation: out = ifft2( fft2(x) * H(lam_c, fy, fx) )
// B=8, C=3, H=W=1024.  Transposed-spectrum pipeline, line-exact global access.
//   ws layout: T[img:24][x:1024][y:1024] complex (column x contiguous in y)
//   K0: build H table in T orientation Htab[lam][kx][ky], pre-scaled by 2^-20
//   K1: fwd row FFT (8 rows/block, wave-private) -> transposed store (64B chunks)
//   K2: per column: fwd FFT -> *H -> inv FFT; one wave per column, contiguous
//       8KB I/O per wave, ZERO block barriers, 32KB LDS -> 20 waves/CU
//   K3: 16-row gather (full 128B lines per block) -> inv row FFT -> planes

#define NIMG 24

__device__ __forceinline__ float2 cadd(float2 a, float2 b){ return make_float2(a.x+b.x, a.y+b.y); }
__device__ __forceinline__ float2 csub(float2 a, float2 b){ return make_float2(a.x-b.x, a.y-b.y); }
__device__ __forceinline__ float2 cmul(float2 a, float c, float s){ return make_float2(a.x*c - a.y*s, a.x*s + a.y*c); }

// swizzled byte offset within an 8KB column buffer for complex index j
__device__ __forceinline__ int SW(int j) {
    int b = j << 3;
    return b ^ (((b >> 7) & 7) << 4);
}

// ---------------- transfer function (mirrors the jnp fp32 chain exactly) ----
__device__ __forceinline__ float2 computeH(float lam, int ky, int kx) {
    int iy = (ky < 512) ? ky : ky - 1024;
    int ix = (kx < 512) ? kx : kx - 1024;
    const double recip = 1.0 / (1024.0 * 8e-06);
    float fy = (float)((double)iy * recip);
    float fx = (float)((double)ix * recip);
    float f2  = __fadd_rn(__fmul_rn(fy, fy), __fmul_rn(fx, fx));
    float l2  = __fmul_rn(lam, lam);
    float arg = __fsub_rn(1.0f, __fmul_rn(l2, f2));
    float2 h = make_float2(0.0f, 0.0f);
    if (arg > 0.0f) {
        float t  = __fdiv_rn(6.28318530717958647692f, lam);
        t        = __fmul_rn(t, 0.05f);
        float kz = __fmul_rn(t, __fsqrt_rn(arg));
        double s, c;
        sincos((double)kz, &s, &c);
        const float sc = 9.5367431640625e-07f;              // 2^-20
        h = make_float2((float)c * sc, (float)s * sc);
    }
    return h;
}

// Htab[c][kx][ky]  (T orientation: contiguous in ky)
__global__ __launch_bounds__(256) void build_H_T(float2* __restrict__ Htab,
                                                 const float* __restrict__ wl) {
    int idx = blockIdx.x * 256 + threadIdx.x;
    int c   = idx >> 20;
    int rem = idx & 1048575;
    Htab[idx] = computeH(wl[c], rem & 1023, rem >> 10);
}

// ---------------- radix-4 butterflies ---------------------------------------
template<int SIGN>
__device__ __forceinline__ void dft4nt(float2& a0, float2& a1, float2& a2, float2& a3) {
    float2 t0 = cadd(a0, a2), t1 = csub(a0, a2);
    float2 t2 = cadd(a1, a3), t3 = csub(a1, a3);
    a0 = cadd(t0, t2);
    a2 = csub(t0, t2);
    a1 = make_float2(t1.x - SIGN * t3.y, t1.y + SIGN * t3.x);
    a3 = make_float2(t1.x + SIGN * t3.y, t1.y - SIGN * t3.x);
}
template<int SIGN>
__device__ __forceinline__ void dft4(float2& a0, float2& a1, float2& a2, float2& a3,
                                     float c1, float s1) {
    float c2 = c1*c1 - s1*s1, s2 = 2.f*c1*s1;
    float c3 = c2*c1 - s2*s1, s3 = s2*c1 + c2*s1;
    a1 = cmul(a1, c1, s1);
    a2 = cmul(a2, c2, s2);
    a3 = cmul(a3, c3, s3);
    dft4nt<SIGN>(a0, a1, a2, a3);
}

#define WSYNC() do { asm volatile("s_waitcnt lgkmcnt(0)" ::: "memory"); \
                     __builtin_amdgcn_wave_barrier(); } while (0)

// ---------------- 1024-pt wave-private FFT over swizzled 8KB LDS column -----
// 64 lanes x 16 complex.  Verified R1-R4.  SIGN=-1 fwd, +1 inv (unnormalized).
template<int SIGN>
__device__ __forceinline__ void wave_fft(char* cb, int l) {
    const float SPI8   = SIGN * 0.39269908169872415481f;   // pi/8
    const float SPI32  = SIGN * 0.09817477042468103870f;   // pi/32
    const float SPI128 = SIGN * 0.02454369260617025967f;   // pi/128
    const float SPI512 = SIGN * 0.00613592315154256492f;   // pi/512
    const int swzE = (((l >> 4)    ) & 7) << 4;
    const int swzO = (((l >> 4) + 4) & 7) << 4;
    char* rbE = cb + ((8 * l) ^ swzE);
    char* rbO = cb + ((8 * l) ^ swzO);
    float2 v[4][4];

    // ---- Round A: stages 0 (j=l+64k) + 1 (j'=4l+q) -------------------------
    #pragma unroll
    for (int k = 0; k < 4; ++k) {
        #pragma unroll
        for (int r = 0; r < 4; ++r) {
            const int tt = k + 4 * r;
            v[k][r] = *(const float2*)(((tt & 1) ? rbO : rbE) + 512 * tt);
        }
    }
    #pragma unroll
    for (int k = 0; k < 4; ++k) dft4nt<SIGN>(v[k][0], v[k][1], v[k][2], v[k][3]);
    dft4nt<SIGN>(v[0][0], v[1][0], v[2][0], v[3][0]);
    #pragma unroll
    for (int q = 1; q < 4; ++q) {
        float s1, c1; __sincosf((float)q * SPI8, &s1, &c1);
        dft4<SIGN>(v[0][q], v[1][q], v[2][q], v[3][q], c1, s1);
    }
    {
        char* wb = cb + 128 * l;
        const int L7 = l & 7;
        #pragma unroll
        for (int p = 0; p < 4; ++p) {
            *(float4*)(wb + 16 * ((2*p+0) ^ L7)) =
                make_float4(v[p][0].x, v[p][0].y, v[p][1].x, v[p][1].y);
            *(float4*)(wb + 16 * ((2*p+1) ^ L7)) =
                make_float4(v[p][2].x, v[p][2].y, v[p][3].x, v[p][3].y);
        }
    }
    WSYNC();

    // ---- Round B: stages 2 (j=l+64k) + 3 (j'=64(l>>4)+(l&15)+16q) ----------
    #pragma unroll
    for (int k = 0; k < 4; ++k) {
        #pragma unroll
        for (int r = 0; r < 4; ++r) {
            const int tt = k + 4 * r;
            v[k][r] = *(const float2*)(((tt & 1) ? rbO : rbE) + 512 * tt);
        }
    }
    {
        const int jm2 = l & 15;
        float s1, c1; __sincosf((float)jm2 * SPI32, &s1, &c1);
        #pragma unroll
        for (int k = 0; k < 4; ++k) dft4<SIGN>(v[k][0], v[k][1], v[k][2], v[k][3], c1, s1);
        const int lo8 = 8 * (l & 15);
        const int hi  = 2048 * (l >> 4);
        #pragma unroll
        for (int q = 0; q < 4; ++q) {
            float s1b, c1b; __sincosf((float)(jm2 + 16 * q) * SPI128, &s1b, &c1b);
            dft4<SIGN>(v[0][q], v[1][q], v[2][q], v[3][q], c1b, s1b);
            #pragma unroll
            for (int p = 0; p < 4; ++p) {
                const int K = ((q + 4 * p) & 7) << 4;
                *(float2*)(cb + (lo8 ^ K) + hi + 128 * q + 512 * p) = v[p][q];
            }
        }
    }
    WSYNC();

    // ---- Round C: stage 4 (j''=l+64m), in-place on {l+64m+256q} ------------
    #pragma unroll
    for (int m = 0; m < 4; ++m) {
        #pragma unroll
        for (int r = 0; r < 4; ++r) {
            const int tt = m + 4 * r;
            v[m][r] = *(const float2*)(((tt & 1) ? rbO : rbE) + 512 * tt);
        }
    }
    #pragma unroll
    for (int m = 0; m < 4; ++m) {
        float s1, c1; __sincosf((float)(l + 64 * m) * SPI512, &s1, &c1);
        dft4<SIGN>(v[m][0], v[m][1], v[m][2], v[m][3], c1, s1);
        #pragma unroll
        for (int q = 0; q < 4; ++q) {
            const int tt = m + 4 * q;
            *(float2*)(((tt & 1) ? rbO : rbE) + 512 * tt) = v[m][q];
        }
    }
}

// ---------------- K1: fwd row FFT + transposed store (verified R3) -----------
// 512 thr = 8 waves, 8 rows/block, 64KB LDS.  Wave w FFTs row y0+w privately.
__global__ __launch_bounds__(512, 4) void k1_rows_T(const float* __restrict__ xr,
                                                    const float* __restrict__ xi,
                                                    float2* __restrict__ T) {
    __shared__ float4 ldsb[4096];
    char* lds = (char*)ldsb;
    const int t = threadIdx.x, w = t >> 6, l = t & 63;
    const int img = blockIdx.x >> 7;
    const int y0  = (blockIdx.x & 127) << 3;
    const long long ib = (long long)img << 20;
    char* cb = lds + 8192 * w;

    // coalesced load of row y0+w (both planes), interleave into private cb
    {
        const float4* rr = (const float4*)(xr + ib + (long long)(y0 + w) * 1024);
        const float4* ri = (const float4*)(xi + ib + (long long)(y0 + w) * 1024);
        const int swz = ((l >> 2) & 7) << 4;
        #pragma unroll
        for (int k = 0; k < 4; ++k) {
            float4 a = rr[64 * k + l], b = ri[64 * k + l];
            *(float4*)(cb + 2048 * k + ((32 * l) ^ swz))      = make_float4(a.x, b.x, a.y, b.y);
            *(float4*)(cb + 2048 * k + ((32 * l + 16) ^ swz)) = make_float4(a.z, b.z, a.w, b.w);
        }
    }
    WSYNC();
    wave_fft<-1>(cb, l);
    __syncthreads();

    // transposed store: T[x][y0 + 2seg..2seg+1], 64B chunks fully covered
    {
        const int seg = t & 3;
        const int xb  = t >> 2;                  // 0..127
        #pragma unroll
        for (int k = 0; k < 8; ++k) {
            int x = xb + 128 * k;
            float2 v0 = *(const float2*)(lds + 8192 * (2 * seg)     + SW(x));
            float2 v1 = *(const float2*)(lds + 8192 * (2 * seg + 1) + SW(x));
            *(float4*)(T + ib + (long long)x * 1024 + y0 + 2 * seg) =
                make_float4(v0.x, v0.y, v1.x, v1.y);
        }
    }
}

// ---------------- K2: column pass, wave-private, barrier-free (verified R3) --
// 256 thr = 4 waves, one T-row (= one original column) per wave.  32KB LDS.
__global__ __launch_bounds__(256, 4) void k2_cols_H(float2* __restrict__ T,
                                                    const float2* __restrict__ Htab,
                                                    const float* __restrict__ wl) {
    __shared__ float4 ldsb[2048];
    char* lds = (char*)ldsb;
    const int t = threadIdx.x, w = t >> 6, l = t & 63;
    const int img = blockIdx.x >> 8;
    const int x   = ((blockIdx.x & 255) << 2) + w;
    const int lamIdx = img % 3;
    char* cb = lds + 8192 * w;
    float2* row = T + ((long long)img << 20) + (long long)x * 1024;
    const int swz = ((l >> 3) & 7) << 4;

    #pragma unroll
    for (int k = 0; k < 8; ++k) {
        float4 g = ((const float4*)row)[64 * k + l];
        *(float4*)(cb + 1024 * k + ((16 * l) ^ swz)) = g;
    }
    WSYNC();
    wave_fft<-1>(cb, l);
    WSYNC();
    {
        const float2* hrow = Htab ? (Htab + ((long long)lamIdx << 20) + (long long)x * 1024)
                                  : nullptr;
        const float lam = Htab ? 0.0f : wl[lamIdx];
        #pragma unroll
        for (int k = 0; k < 8; ++k) {
            float4* p = (float4*)(cb + 1024 * k + ((16 * l) ^ swz));
            float4 a = *p;
            float4 h;
            if (hrow) {
                h = ((const float4*)hrow)[64 * k + l];
            } else {
                int m = 128 * k + 2 * l;
                float2 h0 = computeH(lam, m,     x);
                float2 h1 = computeH(lam, m + 1, x);
                h = make_float4(h0.x, h0.y, h1.x, h1.y);
            }
            *p = make_float4(a.x * h.x - a.y * h.y, a.x * h.y + a.y * h.x,
                             a.z * h.z - a.w * h.w, a.z * h.w + a.w * h.z);
        }
    }
    WSYNC();
    wave_fft<1>(cb, l);
    WSYNC();
    #pragma unroll
    for (int k = 0; k < 8; ++k) {
        float4 g = *(const float4*)(cb + 1024 * k + ((16 * l) ^ swz));
        ((float4*)row)[64 * k + l] = g;
    }
}

// ---------------- K3: 16-row gather (full lines) + inv row FFT -> planes -----
// 1024 thr = 16 waves, 16 rows/block, 128KB dynamic LDS.  Thread t gathers
// column x=t: 128B contiguous (16 complex) covering the whole line.  Then
// wave w FFTs row y0+w privately and stores coalesced.
__global__ __launch_bounds__(1024, 1) void k3_irows_T16(const float2* __restrict__ T,
                                                        float* __restrict__ outr,
                                                        float* __restrict__ outi) {
    extern __shared__ char lds[];                 // 131072 bytes
    const int t = threadIdx.x;                    // 0..1023
    const int img = blockIdx.x >> 6;              // 24 img x 64 y-groups
    const int y0  = (blockIdx.x & 63) << 4;
    const long long ib = (long long)img << 20;

    // gather: thread t = column t; read 16 complex (128B, line-aligned)
    {
        const float4* src = (const float4*)(T + ib + (long long)t * 1024 + y0);
        const int sx = SW(t);
        #pragma unroll
        for (int p = 0; p < 8; ++p) {
            float4 g = src[p];                    // rows y0+2p, y0+2p+1 of col t
            *(float2*)(lds + 8192 * (2 * p)     + sx) = make_float2(g.x, g.y);
            *(float2*)(lds + 8192 * (2 * p + 1) + sx) = make_float2(g.z, g.w);
        }
    }
    __syncthreads();

    const int w = t >> 6, l = t & 63;
    char* cb = lds + 8192 * w;                    // wave w owns row y0+w
    wave_fft<1>(cb, l);
    WSYNC();

    // store row y0+w to real/imag planes, coalesced
    {
        float4* pr = (float4*)(outr + ib + (long long)(y0 + w) * 1024);
        float4* pi = (float4*)(outi + ib + (long long)(y0 + w) * 1024);
        const int swz = ((l >> 2) & 7) << 4;
        #pragma unroll
        for (int k = 0; k < 4; ++k) {
            float4 c0 = *(const float4*)(cb + 2048 * k + ((32 * l) ^ swz));
            float4 c1 = *(const float4*)(cb + 2048 * k + ((32 * l + 16) ^ swz));
            pr[64 * k + l] = make_float4(c0.x, c0.z, c1.x, c1.z);
            pi[64 * k + l] = make_float4(c0.y, c0.w, c1.y, c1.w);
        }
    }
}

// ---------------- launch ------------------------------------------------------
extern "C" void kernel_launch(void* const* d_in, const int* in_sizes, int n_in,
                              void* d_out, int out_size, void* d_ws, size_t ws_size,
                              hipStream_t stream) {
    const float* xr = (const float*)d_in[0];
    const float* xi = (const float*)d_in[1];
    const float* wl = (const float*)d_in[2];
    float* out = (float*)d_out;

    const size_t planeElems = (size_t)NIMG * 1024 * 1024;          // 24M
    float2* wsC = (float2*)d_ws;                                   // 192 MB
    const size_t needC = planeElems * sizeof(float2);
    const size_t needH = (size_t)3 * 1024 * 1024 * sizeof(float2); // 24 MB
    float2* Htab = nullptr;
    if (ws_size >= needC + needH) {
        Htab = (float2*)((char*)d_ws + needC);
        build_H_T<<<12288, 256, 0, stream>>>(Htab, wl);
    }
    k1_rows_T<<<NIMG * 128, 512, 0, stream>>>(xr, xi, wsC);
    k2_cols_H<<<NIMG * 256, 256, 0, stream>>>(wsC, Htab, wl);
    k3_irows_T16<<<NIMG * 64, 1024, 131072, stream>>>(wsC, out, out + planeElems);
}